// Round 1
// 1159.437 us; speedup vs baseline: 1.9209x; 1.9209x over previous
//
#include <hip/hip_runtime.h>
#include <stdint.h>
#include <math.h>

#define R_ 16
#define C_ 256
#define B_ 12
#define E_ 768
#define H_ 12
#define D_ 64
#define TOK (R_*C_*B_)          // 49152

typedef __bf16 bf16x8 __attribute__((ext_vector_type(8)));
typedef float floatx4 __attribute__((ext_vector_type(4)));

__device__ __forceinline__ unsigned short f2bf(float f) {
    union { unsigned int i; float f; } v; v.f = f;
    unsigned int i = v.i;
    return (unsigned short)((i + 0x7fffu + ((i >> 16) & 1u)) >> 16);  // RNE
}
__device__ __forceinline__ bf16x8 cvt8(floatx4 lo, floatx4 hi) {
    bf16x8 r;
    r[0] = (__bf16)lo[0]; r[1] = (__bf16)lo[1]; r[2] = (__bf16)lo[2]; r[3] = (__bf16)lo[3];
    r[4] = (__bf16)hi[0]; r[5] = (__bf16)hi[1]; r[6] = (__bf16)hi[2]; r[7] = (__bf16)hi[3];
    return r;
}

// ---------------------------------------------------------------------------
// 128x128 A*B^T GEMM, batched over n in the grid. d_out is FLOAT32.
// MODE 0: proj q/k (ALL n): A = x tokens [tok][768] f32; Bt = W f32;
//         out bf16 q[tok*768+cc] (tok = m*12+n natural order). grid (6,384).
// MODE 1: scores (ALL h,n):  z = n*12+h. A=q, Bt=k (bf16, K=rd=1024,
//         elem q[((r*256+i)*12+n)*768 + h*64+d]);
//         f32 out -> probs[(h*12+n)*65536 + i*256 + j]. grid (2,2,144).
// MODE 2: PV (chunk of 2 n):  z = nn*12+h, n = nBase+nn.
//         A = probs (h,n) f32 (cvt->bf16), K=j=256;
//         Bt = vt[((nn*12+h)*1024 + rd)*256 + j] bf16;
//         bf16 out ctx[nn][(r*256+i)*768 + h*64 + d]. grid (8,2,24).
// MODE 3: proj v (chunk):     z = nn. f32 in, epilogue ->
//         bf16 vt[nn][(h*1024 + r*64+d)*256 + j]. grid (6,32,2).
// MODE 4: out proj (chunk):   z = nn. A = ctx[nn] bf16; Bt = Wo f32;
//         f32 out rows (m*12+n). grid (6,32,2).
// ---------------------------------------------------------------------------
#define VT_N_ELEMS 3145728   // 12h * 1024rd * 256j shorts per n
#define CTX_N_ELEMS 3145728  // 4096 tok * 768 shorts per n

template<int MODE>
__global__ __launch_bounds__(256)
void gemm_bt(const void* __restrict__ Ap,
             const void* __restrict__ Btp,
             const float* __restrict__ bias,
             void* __restrict__ Cout,
             int nBase)
{
    __shared__ __align__(16) unsigned short As[128 * 32];
    __shared__ __align__(16) unsigned short Bs[128 * 32];

    const int K = (MODE == 1) ? 1024 : ((MODE == 2) ? 256 : 768);

    const int tid  = threadIdx.x;
    const int wave = tid >> 6, lane = tid & 63;
    const int quad = lane >> 4, l15 = lane & 15;
    const int wr = wave >> 1, wc = wave & 1;
    const int row0 = blockIdx.y * 128, col0 = blockIdx.x * 128;

    int hIdx = 0, nn = 0, nIdx = 0;
    if (MODE == 1) { hIdx = blockIdx.z % 12; nIdx = blockIdx.z / 12; }
    if (MODE == 2) { hIdx = blockIdx.z % 12; nn = blockIdx.z / 12; nIdx = nBase + nn; }
    if (MODE == 3 || MODE == 4) { nn = blockIdx.z; nIdx = nBase + nn; }

    const floatx4 zero = {0.f, 0.f, 0.f, 0.f};
    floatx4 acc[4][4];
#pragma unroll
    for (int i = 0; i < 4; ++i)
#pragma unroll
        for (int j = 0; j < 4; ++j) acc[i][j] = zero;

    const int kIters = K >> 5;
    for (int kt = 0; kt < kIters; ++kt) {
        const int k0 = kt << 5;
        bf16x8 ra[2], rbv[2];
#pragma unroll
        for (int it = 0; it < 2; ++it) {
            const int idx = it * 256 + tid;        // 128 rows x 4 k-chunks
            const int row = idx >> 2, ck = idx & 3;
            const int kk = k0 + ck * 8;
            if (MODE == 0) {                       // f32 x tokens, f32 W
                const float* ga = (const float*)Ap + (size_t)(row0 + row) * 768 + kk;
                const float* gb = (const float*)Btp + (size_t)(col0 + row) * 768 + kk;
                ra[it]  = cvt8(((const floatx4*)ga)[0], ((const floatx4*)ga)[1]);
                rbv[it] = cvt8(((const floatx4*)gb)[0], ((const floatx4*)gb)[1]);
            } else if (MODE == 3) {                // f32 x rows (m*12+n), f32 W
                const float* ga = (const float*)Ap
                                  + ((size_t)(row0 + row) * 12 + nIdx) * 768 + kk;
                const float* gb = (const float*)Btp + (size_t)(col0 + row) * 768 + kk;
                ra[it]  = cvt8(((const floatx4*)ga)[0], ((const floatx4*)ga)[1]);
                rbv[it] = cvt8(((const floatx4*)gb)[0], ((const floatx4*)gb)[1]);
            } else if (MODE == 4) {                // bf16 ctx[nn], f32 Wo
                const unsigned short* ga = (const unsigned short*)Ap
                                           + (size_t)nn * CTX_N_ELEMS
                                           + (size_t)(row0 + row) * 768 + kk;
                const float* gb = (const float*)Btp + (size_t)(col0 + row) * 768 + kk;
                ra[it]  = *(const bf16x8*)ga;
                rbv[it] = cvt8(((const floatx4*)gb)[0], ((const floatx4*)gb)[1]);
            } else if (MODE == 1) {                // bf16 q/k, k-dim rd, all-n layout
                const int r = kk >> 6, d = kk & 63;
                ra[it]  = *(const bf16x8*)((const unsigned short*)Ap
                          + ((size_t)(r * 256 + row0 + row) * 12 + nIdx) * 768
                          + hIdx * 64 + d);
                rbv[it] = *(const bf16x8*)((const unsigned short*)Btp
                          + ((size_t)(r * 256 + col0 + row) * 12 + nIdx) * 768
                          + hIdx * 64 + d);
            } else {                               // MODE 2: f32 probs, bf16 vt[nn]
                const float* ga = (const float*)Ap
                                  + ((size_t)(hIdx * 12 + nIdx)) * 65536
                                  + (size_t)(row0 + row) * 256 + kk;
                ra[it]  = cvt8(((const floatx4*)ga)[0], ((const floatx4*)ga)[1]);
                rbv[it] = *(const bf16x8*)((const unsigned short*)Btp
                          + (((size_t)nn * 12 + hIdx) * 1024 + col0 + row) * 256 + kk);
            }
        }
        __syncthreads();   // previous iteration's LDS readers done
#pragma unroll
        for (int it = 0; it < 2; ++it) {
            const int idx = it * 256 + tid;
            *(bf16x8*)(As + (size_t)idx * 8) = ra[it];
            *(bf16x8*)(Bs + (size_t)idx * 8) = rbv[it];
        }
        __syncthreads();   // LDS tiles valid

        bf16x8 af[4], bfr[4];
#pragma unroll
        for (int t = 0; t < 4; ++t) {
            af[t]  = *(const bf16x8*)(As + ((wr * 64 + t * 16 + l15) * 32 + quad * 8));
            bfr[t] = *(const bf16x8*)(Bs + ((wc * 64 + t * 16 + l15) * 32 + quad * 8));
        }
#pragma unroll
        for (int tm = 0; tm < 4; ++tm)
#pragma unroll
            for (int tn = 0; tn < 4; ++tn)
                acc[tm][tn] = __builtin_amdgcn_mfma_f32_16x16x32_bf16(
                    af[tm], bfr[tn], acc[tm][tn], 0, 0, 0);
    }

    // Epilogue. C/D layout: col = lane&15, row = quad*4 + reg.
#pragma unroll
    for (int tm = 0; tm < 4; ++tm) {
        const int rbase = row0 + wr * 64 + tm * 16 + quad * 4;
#pragma unroll
        for (int tn = 0; tn < 4; ++tn) {
            const int cc = col0 + wc * 64 + tn * 16 + l15;
#pragma unroll
            for (int rr = 0; rr < 4; ++rr) {
                float vv = acc[tm][tn][rr];
                const int rowg = rbase + rr;
                if (MODE == 0) {
                    ((unsigned short*)Cout)[(size_t)rowg * 768 + cc] = f2bf(vv + bias[cc]);
                } else if (MODE == 1) {
                    ((float*)Cout)[((size_t)(hIdx * 12 + nIdx)) * 65536
                                   + (size_t)rowg * 256 + cc] = vv * 0.03125f;
                } else if (MODE == 2) {   // ctx[nn][(r*256+i)*768 + h*64 + d]
                    ((unsigned short*)Cout)[(size_t)nn * CTX_N_ELEMS
                                            + (((size_t)(cc >> 6)) * 256 + rowg) * 768
                                            + hIdx * 64 + (cc & 63)] = f2bf(vv);
                } else if (MODE == 3) {   // vt[nn][(h*1024 + r*64+d)*256 + j]
                    ((unsigned short*)Cout)[(size_t)nn * VT_N_ELEMS
                                            + (((size_t)(cc >> 6)) * 1024
                                               + (rowg >> 8) * 64 + (cc & 63)) * 256
                                            + (rowg & 255)] = f2bf(vv + bias[cc]);
                } else {                  // MODE 4: f32 out rows (m*12+n)
                    ((float*)Cout)[((size_t)rowg * 12 + nIdx) * 768 + cc] = vv + bias[cc];
                }
            }
        }
    }
}

// ---------------------------------------------------------------------------
// T5 relative-position buckets (f32 op order matches reference)
// ---------------------------------------------------------------------------
__global__ __launch_bounds__(256)
void bucket_kernel(const int* __restrict__ dist, int* __restrict__ buckets)
{
    const int idx = blockIdx.x * 256 + threadIdx.x;
    if (idx >= B_ * C_ * C_) return;
    const int dv = dist[idx];
    const int n = dv < 0 ? -dv : dv;
    int bkt;
    if (n < 16) {
        bkt = n;
    } else {
        const float lg = logf((float)n * 0.0625f);        // log(n/16)
        const float t  = (lg / 8.047189562170502f) * 15.0f;
        bkt = 16 + (int)t;
        if (bkt > 31) bkt = 31;
    }
    buckets[idx] = bkt;
}

// ---------------------------------------------------------------------------
// In-place f32 bias + softmax over j. One wave per row.
// probs[(h*12+n)*256+i][j], f32. attn[h,n,i,j] += rel_bias[bkt(dist[h,i,j]), n]
// ---------------------------------------------------------------------------
__global__ __launch_bounds__(256)
void softmax_bias(float* __restrict__ probs,
                  const int* __restrict__ buckets,
                  const float* __restrict__ rb)
{
    const int wave = threadIdx.x >> 6, lane = threadIdx.x & 63;
    const int rowid = blockIdx.x * 4 + wave;     // [0, 36864)
    const int p = rowid >> 8;
    const int i = rowid & 255;
    const int a = p / 12, b = p - a * 12;        // a = h, b = n
    float* prow = probs + (size_t)rowid * 256;
    const int* brow = buckets + ((size_t)a * 256 + i) * 256;

    float vals[4];
    float mx = -3.4e38f;
#pragma unroll
    for (int t = 0; t < 4; ++t) {
        const int j = t * 64 + lane;
        vals[t] = prow[j] + rb[brow[j] * 12 + b];
        mx = fmaxf(mx, vals[t]);
    }
#pragma unroll
    for (int off = 32; off > 0; off >>= 1) mx = fmaxf(mx, __shfl_xor(mx, off, 64));
    float sum = 0.f;
#pragma unroll
    for (int t = 0; t < 4; ++t) { vals[t] = expf(vals[t] - mx); sum += vals[t]; }
#pragma unroll
    for (int off = 32; off > 0; off >>= 1) sum += __shfl_xor(sum, off, 64);
    const float inv = 1.f / sum;
#pragma unroll
    for (int t = 0; t < 4; ++t) prow[t * 64 + lane] = vals[t] * inv;
}

// ---------------------------------------------------------------------------
// Memory plan.
// d_out (188,743,680 B):
//   out f32  [0 : 150,994,944)  -- final output; doubles as scratch before
//                                  the out-projection:
//       q bf16 [0 : 75,497,472)           37,748,736 shorts (tok x 768)
//       k bf16 [75,497,472 : 150,994,944) 37,748,736 shorts
//   probs f32 [150,994,944 : 188,743,680) -- scores -> softmax in place (final)
// d_ws (28,311,552 B):
//   vt      : ws +          0  (12,582,912 B)  2n x [12h x 1024rd x 256j] bf16
//   ctx     : ws + 12,582,912  (12,582,912 B)  2n x [4096 tok x 768] bf16
//   buckets : ws + 25,165,824  ( 3,145,728 B)
// Phase order: buckets | q,k proj (ALL n) | scores (ALL h,n) | softmax |
//   6 chunks of 2 n: {v proj -> vt, PV -> ctx, out proj -> out f32}.
// Out-proj writes scatter over the whole out region but q/k are dead by then
// and vt/ctx live in ws, so stream order guarantees correctness.
// ---------------------------------------------------------------------------
extern "C" void kernel_launch(void* const* d_in, const int* in_sizes, int n_in,
                              void* d_out, int out_size, void* d_ws, size_t ws_size,
                              hipStream_t stream)
{
    const float* x    = (const float*)d_in[0];
    const int*   dist = (const int*)d_in[1];
    const float* Wq   = (const float*)d_in[2];
    const float* bq   = (const float*)d_in[3];
    const float* Wk   = (const float*)d_in[4];
    const float* bk   = (const float*)d_in[5];
    const float* Wv   = (const float*)d_in[6];
    const float* bv   = (const float*)d_in[7];
    const float* Wo   = (const float*)d_in[8];
    const float* bo   = (const float*)d_in[9];
    const float* rb   = (const float*)d_in[10];

    float* outp  = (float*)d_out;
    float* probs = (float*)d_out + (size_t)TOK * E_;     // f32 elem 37,748,736

    unsigned short* qs = (unsigned short*)d_out;          // bf16 scratch (out lo)
    unsigned short* ks = (unsigned short*)d_out + 37748736; // bf16 scratch (out hi)

    char* ws = (char*)d_ws;
    unsigned short* vt  = (unsigned short*)(ws);
    unsigned short* ctx = (unsigned short*)(ws + 12582912);
    int* buckets        = (int*)(ws + 25165824);

    dim3 blk(256);

    bucket_kernel<<<dim3(3072), blk, 0, stream>>>(dist, buckets);

    // Phase 1: q/k projection for ALL n (one launch each), then all scores.
    gemm_bt<0><<<dim3(6, 384), blk, 0, stream>>>(x, Wq, bq, qs, 0);
    gemm_bt<0><<<dim3(6, 384), blk, 0, stream>>>(x, Wk, bk, ks, 0);
    gemm_bt<1><<<dim3(2, 2, 144), blk, 0, stream>>>(qs, ks, nullptr, probs, 0);

    // Phase 2: f32 bias + softmax in place (all pairs)
    softmax_bias<<<dim3(9216), blk, 0, stream>>>(probs, buckets, rb);

    // Phase 3: chunks of 2 n: v projection (transposed), PV, out projection
    for (int c = 0; c < 6; ++c) {
        const int n0 = 2 * c;
        gemm_bt<3><<<dim3(6, 32, 2), blk, 0, stream>>>(x, Wv, bv, vt, n0);
        gemm_bt<2><<<dim3(8, 2, 24), blk, 0, stream>>>(probs, vt, nullptr, ctx, n0);
        gemm_bt<4><<<dim3(6, 32, 2), blk, 0, stream>>>(ctx, Wo, bo, outp, n0);
    }
}

// Round 3
// 973.791 us; speedup vs baseline: 2.2871x; 1.1906x over previous
//
#include <hip/hip_runtime.h>
#include <stdint.h>
#include <math.h>

#define R_ 16
#define C_ 256
#define B_ 12
#define E_ 768
#define H_ 12
#define D_ 64
#define TOK (R_*C_*B_)          // 49152

#define VT_N_ELEMS 3145728     // 12h * 1024rd * 256j shorts per n
#define CTX_N_ELEMS 3145728    // 4096 tok * 768 shorts per n
#define QK_HALF 37748736       // shorts per q or k buffer (49152*768)

typedef __bf16 bf16x8 __attribute__((ext_vector_type(8)));
typedef float floatx4 __attribute__((ext_vector_type(4)));

__device__ __forceinline__ unsigned short f2bf(float f) {
    union { unsigned int i; float f; } v; v.f = f;
    unsigned int i = v.i;
    return (unsigned short)((i + 0x7fffu + ((i >> 16) & 1u)) >> 16);  // RNE
}
__device__ __forceinline__ bf16x8 cvt8(floatx4 lo, floatx4 hi) {
    bf16x8 r;
    r[0] = (__bf16)lo[0]; r[1] = (__bf16)lo[1]; r[2] = (__bf16)lo[2]; r[3] = (__bf16)lo[3];
    r[4] = (__bf16)hi[0]; r[5] = (__bf16)hi[1]; r[6] = (__bf16)hi[2]; r[7] = (__bf16)hi[3];
    return r;
}
__device__ __forceinline__ void gload16(const unsigned short* g, unsigned short* l) {
    __builtin_amdgcn_global_load_lds(
        (const __attribute__((address_space(1))) unsigned int*)g,
        (__attribute__((address_space(3))) unsigned int*)l, 16, 0, 0);
}

// ---------------------------------------------------------------------------
// 128x128 A*B^T GEMM. B is ALWAYS bf16 via global_load_lds(16B).
// A: global_load_lds for MODE 1/4 (bf16 src), f32-load+cvt+ds_write otherwise.
// LDS k-chunk XOR swizzle: slot (row,ck) holds logical chunk ck^((row>>1)&3);
// applied on the global SOURCE address (gload_lds dest stays linear).
// XCD swizzle: tiles remapped so each XCD gets contiguous panels, col-fastest.
//
// MODE 0: fused q+k proj. A = x f32 [tok][768]; Bt = wqk_bf [1536][768];
//         grid (12,384). out bf16 q_s/k_s[((n*12+h)*256+i)*1024 + r*64+d].
// MODE 1: scores. z=n*12+h. A=q_s, Bt=k_s rows contiguous (K=1024).
//         grid (2,2,144). f32 out probs[(h*12+n)*65536 + i*256+j] * 0.03125.
// MODE 2: PV (chunk of 2 n). z=nn*12+h. A=probs f32 (cvt), K=256;
//         Bt = vt[((nn*12+h)*1024+rd)*256+j]. grid (8,2,24).
//         out bf16 ctx[nn][(r*256+i)*768 + h*64+d].
// MODE 3: v proj (chunk). z=nn. A = x f32 rows (m*12+n); Bt = wv_bf.
//         grid (6,32,2). out bf16 vt[nn][(h*1024+r*64+d)*256 + j].
// MODE 4: out proj (chunk). z=nn. A = ctx[nn] bf16; Bt = wo_bf.
//         grid (6,32,2). f32 out rows (m*12+n).
// ---------------------------------------------------------------------------
template<int MODE>
__global__ __launch_bounds__(256)
void gemm_bt(const void* __restrict__ Ap,
             const void* __restrict__ Btp,
             const float* __restrict__ bias,
             void* __restrict__ Cout,
             int nBase)
{
    constexpr bool AGL = (MODE == 1 || MODE == 4);
    constexpr int K = (MODE == 1) ? 1024 : ((MODE == 2) ? 256 : 768);
    constexpr int kIters = K >> 5;
    constexpr int GX = (MODE==0) ? 12 : (MODE==1) ? 2 : (MODE==2) ? 8 : 6;
    constexpr int GY = (MODE==0) ? 384 : (MODE==1) ? 2 : (MODE==2) ? 2 : 32;
    constexpr int GZ = (MODE==0) ? 1 : (MODE==1) ? 144 : (MODE==2) ? 24 : 2;

    __shared__ __align__(16) unsigned short As[128 * 32];
    __shared__ __align__(16) unsigned short Bs[128 * 32];

    const int tid  = threadIdx.x;
    const int wave = tid >> 6, lane = tid & 63;
    const int quad = lane >> 4, l15 = lane & 15;
    const int wr = wave >> 1, wc = wave & 1;

    // XCD swizzle: same (lin % 8) => same XCD (round-robin assumption);
    // within an XCD, consecutive tiles iterate cols of one row-panel first.
    const int lin = ((int)blockIdx.z * GY + (int)blockIdx.y) * GX + (int)blockIdx.x;
    const int tt  = (lin & 7) * ((GX * GY * GZ) >> 3) + (lin >> 3);
    const int bx  = tt % GX;
    const int rem = tt / GX;
    const int by  = rem % GY, bz = rem / GY;
    const int row0 = by * 128, col0 = bx * 128;

    int hIdx = 0, nn = 0, nIdx = 0;
    if (MODE == 1) { hIdx = bz % 12; nIdx = bz / 12; }
    if (MODE == 2) { hIdx = bz % 12; nn = bz / 12; nIdx = nBase + nn; }
    if (MODE == 3 || MODE == 4) { nn = bz; nIdx = nBase + nn; }

    // staging geometry: slot idx = it*256+tid -> row = idx>>2, ck = idx&3.
    // LDS slot (row,ck) holds logical k-chunk (ck ^ sw), sw = (row>>1)&3.
    // (sw is identical for it0/it1 since row1 = row0+64.)
    const int rA0 = tid >> 2;
    const int ck  = tid & 3;
    const int sw  = (tid >> 3) & 3;
    const int kko = ((ck ^ sw) << 3);      // element offset of sourced chunk

    // ---- B row base pointers (bf16, GL) ----
    const unsigned short* Bt = (const unsigned short*)Btp;
    const unsigned short *gB0, *gB1;
    if (MODE == 1) {
        gB0 = Bt + ((size_t)bz * 256 + col0 + rA0) * 1024 + kko;
        gB1 = Bt + ((size_t)bz * 256 + col0 + rA0 + 64) * 1024 + kko;
    } else if (MODE == 2) {
        gB0 = Bt + (((size_t)nn * 12 + hIdx) * 1024 + col0 + rA0) * 256 + kko;
        gB1 = Bt + (((size_t)nn * 12 + hIdx) * 1024 + col0 + rA0 + 64) * 256 + kko;
    } else {
        gB0 = Bt + (size_t)(col0 + rA0) * 768 + kko;
        gB1 = Bt + (size_t)(col0 + rA0 + 64) * 768 + kko;
    }

    // ---- A row base pointers ----
    const unsigned short* gA0u = nullptr; const unsigned short* gA1u = nullptr;
    const float* gA0f = nullptr; const float* gA1f = nullptr;
    if (MODE == 1) {
        gA0u = (const unsigned short*)Ap + ((size_t)bz * 256 + row0 + rA0) * 1024 + kko;
        gA1u = (const unsigned short*)Ap + ((size_t)bz * 256 + row0 + rA0 + 64) * 1024 + kko;
    } else if (MODE == 4) {
        gA0u = (const unsigned short*)Ap + (size_t)nn * CTX_N_ELEMS
               + (size_t)(row0 + rA0) * 768 + kko;
        gA1u = (const unsigned short*)Ap + (size_t)nn * CTX_N_ELEMS
               + (size_t)(row0 + rA0 + 64) * 768 + kko;
    } else if (MODE == 0) {
        gA0f = (const float*)Ap + (size_t)(row0 + rA0) * 768 + kko;
        gA1f = (const float*)Ap + (size_t)(row0 + rA0 + 64) * 768 + kko;
    } else if (MODE == 3) {
        gA0f = (const float*)Ap + ((size_t)(row0 + rA0) * 12 + nIdx) * 768 + kko;
        gA1f = (const float*)Ap + ((size_t)(row0 + rA0 + 64) * 12 + nIdx) * 768 + kko;
    } else { // MODE 2
        gA0f = (const float*)Ap + ((size_t)(hIdx * 12 + nIdx)) * 65536
               + (size_t)(row0 + rA0) * 256 + kko;
        gA1f = (const float*)Ap + ((size_t)(hIdx * 12 + nIdx)) * 65536
               + (size_t)(row0 + rA0 + 64) * 256 + kko;
    }

    // wave-uniform LDS bases for gload_lds (lane deposits at base + lane*16B)
    unsigned short* lA0 = As + wave * 512;
    unsigned short* lA1 = As + 2048 + wave * 512;
    unsigned short* lB0 = Bs + wave * 512;
    unsigned short* lB1 = Bs + 2048 + wave * 512;

    const floatx4 zero = {0.f, 0.f, 0.f, 0.f};
    floatx4 acc[4][4];
#pragma unroll
    for (int i = 0; i < 4; ++i)
#pragma unroll
        for (int j = 0; j < 4; ++j) acc[i][j] = zero;

    // fragment read swizzle: chunk = quad ^ ((l15>>1)&3)
    const int chO = ((quad ^ ((l15 >> 1) & 3)) << 3);   // shorts

    floatx4 u0l = zero, u0h = zero, u1l = zero, u1h = zero;
    floatx4 p0l = zero, p0h = zero, p1l = zero, p1h = zero;
    if (!AGL) {
        u0l = *(const floatx4*)(gA0f);     u0h = *(const floatx4*)(gA0f + 4);
        u1l = *(const floatx4*)(gA1f);     u1h = *(const floatx4*)(gA1f + 4);
    }

#define GSTEP(KT, UL0, UH0, UL1, UH1, PL0, PH0, PL1, PH1)                         \
    {                                                                              \
        __syncthreads();  /* prev LDS readers done; drains A prefetch */           \
        gload16(gB0 + (KT) * 32, lB0);                                             \
        gload16(gB1 + (KT) * 32, lB1);                                             \
        if (AGL) {                                                                 \
            gload16(gA0u + (KT) * 32, lA0);                                        \
            gload16(gA1u + (KT) * 32, lA1);                                        \
        } else {                                                                   \
            *(bf16x8*)(As + tid * 8)        = cvt8(UL0, UH0);                      \
            *(bf16x8*)(As + 2048 + tid * 8) = cvt8(UL1, UH1);                      \
        }                                                                          \
        __syncthreads();  /* LDS tiles valid (drains gload_lds + ds_write) */      \
        if (!AGL && ((KT) + 1 < kIters)) {  /* prefetch overlaps MFMA */           \
            PL0 = *(const floatx4*)(gA0f + ((KT) + 1) * 32);                       \
            PH0 = *(const floatx4*)(gA0f + ((KT) + 1) * 32 + 4);                   \
            PL1 = *(const floatx4*)(gA1f + ((KT) + 1) * 32);                       \
            PH1 = *(const floatx4*)(gA1f + ((KT) + 1) * 32 + 4);                   \
        }                                                                          \
        bf16x8 af[4], bfr[4];                                                      \
        _Pragma("unroll")                                                          \
        for (int t = 0; t < 4; ++t) {                                              \
            af[t]  = *(const bf16x8*)(As + (wr * 64 + t * 16 + l15) * 32 + chO);   \
            bfr[t] = *(const bf16x8*)(Bs + (wc * 64 + t * 16 + l15) * 32 + chO);   \
        }                                                                          \
        _Pragma("unroll")                                                          \
        for (int tm = 0; tm < 4; ++tm)                                             \
            _Pragma("unroll")                                                      \
            for (int tn = 0; tn < 4; ++tn)                                         \
                acc[tm][tn] = __builtin_amdgcn_mfma_f32_16x16x32_bf16(             \
                    af[tm], bfr[tn], acc[tm][tn], 0, 0, 0);                        \
    }

    for (int kt = 0; kt < kIters; kt += 2) {
        GSTEP(kt,     u0l, u0h, u1l, u1h, p0l, p0h, p1l, p1h);
        GSTEP(kt + 1, p0l, p0h, p1l, p1h, u0l, u0h, u1l, u1h);
    }
#undef GSTEP

    // Epilogue. C/D layout: col = lane&15, row = quad*4 + reg.
#pragma unroll
    for (int tm = 0; tm < 4; ++tm) {
        const int rbase = row0 + wr * 64 + tm * 16 + quad * 4;
#pragma unroll
        for (int tn = 0; tn < 4; ++tn) {
            const int cc = col0 + wc * 64 + tn * 16 + l15;
#pragma unroll
            for (int rr = 0; rr < 4; ++rr) {
                float vv = acc[tm][tn][rr];
                const int rowg = rbase + rr;
                if (MODE == 0) {     // q_s/k_s[((n*12+h)*256+i)*1024 + r*64+d]
                    const int m = rowg / 12, n = rowg - m * 12;
                    const int r = m >> 8, i = m & 255;
                    const int sel = cc >= 768 ? 1 : 0;
                    const int ccl = cc - sel * 768;
                    const int h = ccl >> 6, d = ccl & 63;
                    ((unsigned short*)Cout)[(size_t)sel * QK_HALF
                        + ((size_t)(n * 12 + h) * 256 + i) * 1024 + r * 64 + d]
                        = f2bf(vv + bias[cc]);
                } else if (MODE == 1) {
                    ((float*)Cout)[((size_t)(hIdx * 12 + nIdx)) * 65536
                                   + (size_t)rowg * 256 + cc] = vv * 0.03125f;
                } else if (MODE == 2) {   // ctx[nn][(r*256+i)*768 + h*64+d]
                    ((unsigned short*)Cout)[(size_t)nn * CTX_N_ELEMS
                        + (((size_t)(cc >> 6)) * 256 + rowg) * 768
                        + hIdx * 64 + (cc & 63)] = f2bf(vv);
                } else if (MODE == 3) {   // vt[nn][(h*1024 + r*64+d)*256 + j]
                    ((unsigned short*)Cout)[(size_t)nn * VT_N_ELEMS
                        + (((size_t)(cc >> 6)) * 1024
                           + (rowg >> 8) * 64 + (cc & 63)) * 256
                        + (rowg & 255)] = f2bf(vv + bias[cc]);
                } else {                  // MODE 4: f32 out rows (m*12+n)
                    ((float*)Cout)[((size_t)rowg * 12 + nIdx) * 768 + cc] = vv + bias[cc];
                }
            }
        }
    }
}

// ---------------------------------------------------------------------------
// f32 -> bf16 bulk convert (weights), 8 elems/thread. n multiple of 2048.
// ---------------------------------------------------------------------------
__global__ __launch_bounds__(256)
void cvt_w(const float* __restrict__ src, unsigned short* __restrict__ dst, int n)
{
    const int i = (blockIdx.x * 256 + threadIdx.x) * 8;
    if (i >= n) return;
    floatx4 a = ((const floatx4*)(src + i))[0];
    floatx4 b = ((const floatx4*)(src + i))[1];
    *(bf16x8*)(dst + i) = cvt8(a, b);
}

// ---------------------------------------------------------------------------
// T5 relative-position buckets (f32 op order matches reference)
// ---------------------------------------------------------------------------
__global__ __launch_bounds__(256)
void bucket_kernel(const int* __restrict__ dist, int* __restrict__ buckets)
{
    const int idx = blockIdx.x * 256 + threadIdx.x;
    if (idx >= B_ * C_ * C_) return;
    const int dv = dist[idx];
    const int n = dv < 0 ? -dv : dv;
    int bkt;
    if (n < 16) {
        bkt = n;
    } else {
        const float lg = logf((float)n * 0.0625f);        // log(n/16)
        const float t  = (lg / 8.047189562170502f) * 15.0f;
        bkt = 16 + (int)t;
        if (bkt > 31) bkt = 31;
    }
    buckets[idx] = bkt;
}

// ---------------------------------------------------------------------------
// In-place f32 bias + softmax over j. One wave per row.
// probs[(h*12+n)*256+i][j], f32. attn[h,n,i,j] += rel_bias[bkt(dist[h,i,j]), n]
// ---------------------------------------------------------------------------
__global__ __launch_bounds__(256)
void softmax_bias(float* __restrict__ probs,
                  const int* __restrict__ buckets,
                  const float* __restrict__ rb)
{
    const int wave = threadIdx.x >> 6, lane = threadIdx.x & 63;
    const int rowid = blockIdx.x * 4 + wave;     // [0, 36864)
    const int p = rowid >> 8;
    const int i = rowid & 255;
    const int a = p / 12, b = p - a * 12;        // a = h, b = n
    float* prow = probs + (size_t)rowid * 256;
    const int* brow = buckets + ((size_t)a * 256 + i) * 256;

    float vals[4];
    float mx = -3.4e38f;
#pragma unroll
    for (int t = 0; t < 4; ++t) {
        const int j = t * 64 + lane;
        vals[t] = prow[j] + rb[brow[j] * 12 + b];
        mx = fmaxf(mx, vals[t]);
    }
#pragma unroll
    for (int off = 32; off > 0; off >>= 1) mx = fmaxf(mx, __shfl_xor(mx, off, 64));
    float sum = 0.f;
#pragma unroll
    for (int t = 0; t < 4; ++t) { vals[t] = expf(vals[t] - mx); sum += vals[t]; }
#pragma unroll
    for (int off = 32; off > 0; off >>= 1) sum += __shfl_xor(sum, off, 64);
    const float inv = 1.f / sum;
#pragma unroll
    for (int t = 0; t < 4; ++t) prow[t * 64 + lane] = vals[t] * inv;
}

// ---------------------------------------------------------------------------
// Memory plan.
// d_out (188,743,680 B):
//   out f32   [0 : 150,994,944)  -- final; doubles as scratch before out-proj:
//     q_s bf16 [0 : 75,497,472)            (shorts, [n][h][i][rd] layout)
//     k_s bf16 [75,497,472 : 150,994,944)
//   probs f32 [150,994,944 : 188,743,680)  -- scores -> softmax in place (final)
// d_ws (28,311,552 B):
//   wv_bf   @ 0          (1,179,648)
//   wo_bf   @ 1,179,648  (1,179,648)
//   bqk f32 @ 2,359,296  (6,144)
//   wqk_bf  @ 2,365,440  (2,359,296)  [dead after qk-proj]
//   buckets @ 4,724,736  (3,145,728)  [dead after softmax]
//   phase3: vt  @ 2,365,440 (12,582,912)  [over wqk_bf+buckets]
//           ctx @ 14,948,352 (12,582,912) -> ends 27,531,264 <= ws_size
// ---------------------------------------------------------------------------
extern "C" void kernel_launch(void* const* d_in, const int* in_sizes, int n_in,
                              void* d_out, int out_size, void* d_ws, size_t ws_size,
                              hipStream_t stream)
{
    const float* x    = (const float*)d_in[0];
    const int*   dist = (const int*)d_in[1];
    const float* Wq   = (const float*)d_in[2];
    const float* bq   = (const float*)d_in[3];
    const float* Wk   = (const float*)d_in[4];
    const float* bk   = (const float*)d_in[5];
    const float* Wv   = (const float*)d_in[6];
    const float* bv   = (const float*)d_in[7];
    const float* Wo   = (const float*)d_in[8];
    const float* bo   = (const float*)d_in[9];
    const float* rb   = (const float*)d_in[10];

    float* outp  = (float*)d_out;
    float* probs = (float*)d_out + (size_t)TOK * E_;      // f32 elem 37,748,736

    unsigned short* qs = (unsigned short*)d_out;          // [n][h][i][rd]
    unsigned short* ks = (unsigned short*)d_out + QK_HALF;

    char* ws = (char*)d_ws;
    unsigned short* wv_bf  = (unsigned short*)(ws);
    unsigned short* wo_bf  = (unsigned short*)(ws + 1179648);
    float*          bqk    = (float*)(ws + 2359296);
    unsigned short* wqk_bf = (unsigned short*)(ws + 2365440);
    int*            buckets= (int*)(ws + 4724736);
    unsigned short* vt     = (unsigned short*)(ws + 2365440);   // reuse
    unsigned short* ctx    = (unsigned short*)(ws + 14948352);

    dim3 blk(256);

    // weight conversion + bias concat (tiny)
    cvt_w<<<dim3(288), blk, 0, stream>>>(Wq, wqk_bf, 589824);
    cvt_w<<<dim3(288), blk, 0, stream>>>(Wk, wqk_bf + 589824, 589824);
    cvt_w<<<dim3(288), blk, 0, stream>>>(Wv, wv_bf, 589824);
    cvt_w<<<dim3(288), blk, 0, stream>>>(Wo, wo_bf, 589824);
    hipMemcpyAsync(bqk,       bq, 768 * 4, hipMemcpyDeviceToDevice, stream);
    hipMemcpyAsync(bqk + 768, bk, 768 * 4, hipMemcpyDeviceToDevice, stream);

    bucket_kernel<<<dim3(3072), blk, 0, stream>>>(dist, buckets);

    // Phase 1: fused q+k projection (one launch), then all scores.
    gemm_bt<0><<<dim3(12, 384), blk, 0, stream>>>(x, wqk_bf, bqk, qs, 0);
    gemm_bt<1><<<dim3(2, 2, 144), blk, 0, stream>>>(qs, ks, nullptr, probs, 0);

    // Phase 2: f32 bias + softmax in place (all pairs)
    softmax_bias<<<dim3(9216), blk, 0, stream>>>(probs, buckets, rb);

    // Phase 3: chunks of 2 n: v projection (transposed), PV, out projection
    for (int c = 0; c < 6; ++c) {
        const int n0 = 2 * c;
        gemm_bt<3><<<dim3(6, 32, 2), blk, 0, stream>>>(x, wv_bf, bv, vt, n0);
        gemm_bt<2><<<dim3(8, 2, 24), blk, 0, stream>>>(probs, vt, nullptr, ctx, n0);
        gemm_bt<4><<<dim3(6, 32, 2), blk, 0, stream>>>(ctx, wo_bf, bo, outp, n0);
    }
}

// Round 6
// 873.289 us; speedup vs baseline: 2.5503x; 1.1151x over previous
//
#include <hip/hip_runtime.h>
#include <stdint.h>
#include <math.h>

#define R_ 16
#define C_ 256
#define B_ 12
#define E_ 768
#define H_ 12
#define D_ 64
#define TOK (R_*C_*B_)          // 49152
#define HALF_TOK 24576

#define VT_N_ELEMS 3145728     // 12h * 1024rd * 256j shorts per n
#define CTX_N_ELEMS 3145728    // 4096 tok * 768 shorts per n
#define QK_HALF 37748736       // shorts per q or k buffer (49152*768)

typedef __bf16 bf16x8 __attribute__((ext_vector_type(8)));
typedef float floatx4 __attribute__((ext_vector_type(4)));

__device__ __forceinline__ unsigned short f2bf(float f) {
    union { unsigned int i; float f; } v; v.f = f;
    unsigned int i = v.i;
    return (unsigned short)((i + 0x7fffu + ((i >> 16) & 1u)) >> 16);  // RNE
}
__device__ __forceinline__ bf16x8 cvt8(floatx4 lo, floatx4 hi) {
    bf16x8 r;
    r[0] = (__bf16)lo[0]; r[1] = (__bf16)lo[1]; r[2] = (__bf16)lo[2]; r[3] = (__bf16)lo[3];
    r[4] = (__bf16)hi[0]; r[5] = (__bf16)hi[1]; r[6] = (__bf16)hi[2]; r[7] = (__bf16)hi[3];
    return r;
}
__device__ __forceinline__ void gload16(const unsigned short* g, unsigned short* l) {
    __builtin_amdgcn_global_load_lds(
        (const __attribute__((address_space(1))) unsigned int*)g,
        (__attribute__((address_space(3))) unsigned int*)l, 16, 0, 0);
}

// ---------------------------------------------------------------------------
// 128x128 A*B^T GEMM body. B is ALWAYS bf16 via global_load_lds(16B).
// A via global_load_lds for MODE 0/1/4 (bf16 src), f32-load+cvt+ds_write else.
// LDS k-chunk XOR swizzle on global SOURCE addr (kko), inverse on frag read.
// XCD swizzle: same (lin%8) => same XCD; within XCD, col-fastest panels.
//
// MODE 0: q+k proj, HALF of tokens. A = x_bf bf16 [24576][768] (half nBase);
//         Bt = wqk_bf [1536][768]; grid (12,192).
//         out bf16 q_s/k_s[((n*12+h)*256+i)*1024 + r*64+d] (global token).
// MODE 1: scores. z=n*12+h. A=q_s, Bt=k_s rows contiguous (K=1024).
//         grid (2,2,144). f32 out probs[(h*12+n)*65536 + i*256+j] * 0.03125.
// MODE 2: PV (chunk of 2 n). z=nn*12+h. A=probs f32 (cvt), K=256;
//         Bt = vt[((nn*12+h)*1024+rd)*256+j]. grid (8,2,24).
//         out bf16 ctx[nn][(r*256+i)*768 + h*64+d].
// MODE 3: v proj (chunk). z=nn. A = x f32 rows (m*12+n); Bt = wv_bf.
//         grid (6,32,2). out bf16 vt[nn][(h*1024+r*64+d)*256 + j].
// MODE 4: out proj (chunk). z=nn. A = ctx[nn] bf16; Bt = wo_bf.
//         grid (6,32,2). f32 out rows (m*12+n).
// ---------------------------------------------------------------------------
template<int MODE>
__device__ __forceinline__ void gemm_body(const void* __restrict__ Ap,
                                          const void* __restrict__ Btp,
                                          const float* __restrict__ bias,
                                          void* __restrict__ Cout,
                                          int nBase, int rbx, int rby, int rbz,
                                          unsigned short* As, unsigned short* Bs)
{
    constexpr bool AGL = (MODE == 0 || MODE == 1 || MODE == 4);
    constexpr int K = (MODE == 1) ? 1024 : ((MODE == 2) ? 256 : 768);
    constexpr int kIters = K >> 5;
    constexpr int GX = (MODE==0) ? 12 : (MODE==1) ? 2 : (MODE==2) ? 8 : 6;
    constexpr int GY = (MODE==0) ? 192 : (MODE==1) ? 2 : (MODE==2) ? 2 : 32;
    constexpr int GZ = (MODE==0) ? 1 : (MODE==1) ? 144 : (MODE==2) ? 24 : 2;

    const int tid  = threadIdx.x;
    const int wave = tid >> 6, lane = tid & 63;
    const int quad = lane >> 4, l15 = lane & 15;
    const int wr = wave >> 1, wc = wave & 1;

    const int lin = (rbz * GY + rby) * GX + rbx;
    const int tt  = (lin & 7) * ((GX * GY * GZ) >> 3) + (lin >> 3);
    const int bx  = tt % GX;
    const int rem = tt / GX;
    const int by  = rem % GY, bz = rem / GY;
    const int row0 = by * 128, col0 = bx * 128;

    int hIdx = 0, nn = 0, nIdx = 0;
    if (MODE == 1) { hIdx = bz % 12; nIdx = bz / 12; }
    if (MODE == 2) { hIdx = bz % 12; nn = bz / 12; nIdx = nBase + nn; }
    if (MODE == 3 || MODE == 4) { nn = bz; nIdx = nBase + nn; }

    // staging: slot idx = it*256+tid -> row = idx>>2, ck = idx&3.
    // LDS slot (row,ck) holds logical k-chunk (ck ^ sw), sw = (row>>1)&3.
    const int rA0 = tid >> 2;
    const int ck  = tid & 3;
    const int sw  = (tid >> 3) & 3;
    const int kko = ((ck ^ sw) << 3);      // element offset of sourced chunk

    // ---- B row base pointers (bf16, GL) ----
    const unsigned short* Bt = (const unsigned short*)Btp;
    const unsigned short *gB0, *gB1;
    if (MODE == 1) {
        gB0 = Bt + ((size_t)bz * 256 + col0 + rA0) * 1024 + kko;
        gB1 = Bt + ((size_t)bz * 256 + col0 + rA0 + 64) * 1024 + kko;
    } else if (MODE == 2) {
        gB0 = Bt + (((size_t)nn * 12 + hIdx) * 1024 + col0 + rA0) * 256 + kko;
        gB1 = Bt + (((size_t)nn * 12 + hIdx) * 1024 + col0 + rA0 + 64) * 256 + kko;
    } else {
        gB0 = Bt + (size_t)(col0 + rA0) * 768 + kko;
        gB1 = Bt + (size_t)(col0 + rA0 + 64) * 768 + kko;
    }

    // ---- A row base pointers ----
    const unsigned short* gA0u = nullptr; const unsigned short* gA1u = nullptr;
    const float* gA0f = nullptr; const float* gA1f = nullptr;
    if (MODE == 0) {
        gA0u = (const unsigned short*)Ap + (size_t)(row0 + rA0) * 768 + kko;
        gA1u = (const unsigned short*)Ap + (size_t)(row0 + rA0 + 64) * 768 + kko;
    } else if (MODE == 1) {
        gA0u = (const unsigned short*)Ap + ((size_t)bz * 256 + row0 + rA0) * 1024 + kko;
        gA1u = (const unsigned short*)Ap + ((size_t)bz * 256 + row0 + rA0 + 64) * 1024 + kko;
    } else if (MODE == 4) {
        gA0u = (const unsigned short*)Ap + (size_t)nn * CTX_N_ELEMS
               + (size_t)(row0 + rA0) * 768 + kko;
        gA1u = (const unsigned short*)Ap + (size_t)nn * CTX_N_ELEMS
               + (size_t)(row0 + rA0 + 64) * 768 + kko;
    } else if (MODE == 3) {
        gA0f = (const float*)Ap + ((size_t)(row0 + rA0) * 12 + nIdx) * 768 + kko;
        gA1f = (const float*)Ap + ((size_t)(row0 + rA0 + 64) * 12 + nIdx) * 768 + kko;
    } else { // MODE 2
        gA0f = (const float*)Ap + ((size_t)(hIdx * 12 + nIdx)) * 65536
               + (size_t)(row0 + rA0) * 256 + kko;
        gA1f = (const float*)Ap + ((size_t)(hIdx * 12 + nIdx)) * 65536
               + (size_t)(row0 + rA0 + 64) * 256 + kko;
    }

    // wave-uniform LDS bases for gload_lds (lane deposits at base + lane*16B)
    unsigned short* lA0 = As + wave * 512;
    unsigned short* lA1 = As + 2048 + wave * 512;
    unsigned short* lB0 = Bs + wave * 512;
    unsigned short* lB1 = Bs + 2048 + wave * 512;

    const floatx4 zero = {0.f, 0.f, 0.f, 0.f};
    floatx4 acc[4][4];
#pragma unroll
    for (int i = 0; i < 4; ++i)
#pragma unroll
        for (int j = 0; j < 4; ++j) acc[i][j] = zero;

    // fragment read swizzle: chunk = quad ^ ((l15>>1)&3)
    const int chO = ((quad ^ ((l15 >> 1) & 3)) << 3);   // shorts

    floatx4 u0l = zero, u0h = zero, u1l = zero, u1h = zero;
    floatx4 p0l = zero, p0h = zero, p1l = zero, p1h = zero;
    if (!AGL) {
        u0l = *(const floatx4*)(gA0f);     u0h = *(const floatx4*)(gA0f + 4);
        u1l = *(const floatx4*)(gA1f);     u1h = *(const floatx4*)(gA1f + 4);
    }

#define GSTEP(KT, UL0, UH0, UL1, UH1, PL0, PH0, PL1, PH1)                         \
    {                                                                              \
        __syncthreads();  /* prev LDS readers done */                              \
        gload16(gB0 + (KT) * 32, lB0);                                             \
        gload16(gB1 + (KT) * 32, lB1);                                             \
        if (AGL) {                                                                 \
            gload16(gA0u + (KT) * 32, lA0);                                        \
            gload16(gA1u + (KT) * 32, lA1);                                        \
        } else {                                                                   \
            *(bf16x8*)(As + tid * 8)        = cvt8(UL0, UH0);                      \
            *(bf16x8*)(As + 2048 + tid * 8) = cvt8(UL1, UH1);                      \
        }                                                                          \
        __syncthreads();  /* LDS tiles valid */                                    \
        if (!AGL && ((KT) + 1 < kIters)) {  /* prefetch overlaps MFMA */           \
            PL0 = *(const floatx4*)(gA0f + ((KT) + 1) * 32);                       \
            PH0 = *(const floatx4*)(gA0f + ((KT) + 1) * 32 + 4);                   \
            PL1 = *(const floatx4*)(gA1f + ((KT) + 1) * 32);                       \
            PH1 = *(const floatx4*)(gA1f + ((KT) + 1) * 32 + 4);                   \
        }                                                                          \
        bf16x8 af[4], bfr[4];                                                      \
        _Pragma("unroll")                                                          \
        for (int t = 0; t < 4; ++t) {                                              \
            af[t]  = *(const bf16x8*)(As + (wr * 64 + t * 16 + l15) * 32 + chO);   \
            bfr[t] = *(const bf16x8*)(Bs + (wc * 64 + t * 16 + l15) * 32 + chO);   \
        }                                                                          \
        _Pragma("unroll")                                                          \
        for (int tm = 0; tm < 4; ++tm)                                             \
            _Pragma("unroll")                                                      \
            for (int tn = 0; tn < 4; ++tn)                                         \
                acc[tm][tn] = __builtin_amdgcn_mfma_f32_16x16x32_bf16(             \
                    af[tm], bfr[tn], acc[tm][tn], 0, 0, 0);                        \
    }

    for (int kt = 0; kt < kIters; kt += 2) {
        GSTEP(kt,     u0l, u0h, u1l, u1h, p0l, p0h, p1l, p1h);
        GSTEP(kt + 1, p0l, p0h, p1l, p1h, u0l, u0h, u1l, u1h);
    }
#undef GSTEP

    // Epilogue. C/D layout: col = lane&15, row = quad*4 + reg.
#pragma unroll
    for (int tm = 0; tm < 4; ++tm) {
        const int rbase = row0 + wr * 64 + tm * 16 + quad * 4;
#pragma unroll
        for (int tn = 0; tn < 4; ++tn) {
            const int cc = col0 + wc * 64 + tn * 16 + l15;
#pragma unroll
            for (int rr = 0; rr < 4; ++rr) {
                float vv = acc[tm][tn][rr];
                const int rowg = rbase + rr;
                if (MODE == 0) {     // q_s/k_s[((n*12+h)*256+i)*1024 + r*64+d]
                    const int tg = nBase * HALF_TOK + rowg;   // global token
                    const int m = tg / 12, n = tg - m * 12;
                    const int r = m >> 8, i = m & 255;
                    const int sel = cc >= 768 ? 1 : 0;
                    const int ccl = cc - sel * 768;
                    const int h = ccl >> 6, d = ccl & 63;
                    ((unsigned short*)Cout)[(size_t)sel * QK_HALF
                        + ((size_t)(n * 12 + h) * 256 + i) * 1024 + r * 64 + d]
                        = f2bf(vv + bias[cc]);
                } else if (MODE == 1) {
                    ((float*)Cout)[((size_t)(hIdx * 12 + nIdx)) * 65536
                                   + (size_t)rowg * 256 + cc] = vv * 0.03125f;
                } else if (MODE == 2) {   // ctx[nn][(r*256+i)*768 + h*64+d]
                    ((unsigned short*)Cout)[(size_t)nn * CTX_N_ELEMS
                        + (((size_t)(cc >> 6)) * 256 + rowg) * 768
                        + hIdx * 64 + (cc & 63)] = f2bf(vv);
                } else if (MODE == 3) {   // vt[nn][(h*1024 + r*64+d)*256 + j]
                    ((unsigned short*)Cout)[(size_t)nn * VT_N_ELEMS
                        + (((size_t)(cc >> 6)) * 1024
                           + (rowg >> 8) * 64 + (cc & 63)) * 256
                        + (rowg & 255)] = f2bf(vv + bias[cc]);
                } else {                  // MODE 4: f32 out rows (m*12+n)
                    ((float*)Cout)[((size_t)rowg * 12 + nIdx) * 768 + cc] = vv + bias[cc];
                }
            }
        }
    }
}

template<int MODE>
__global__ __launch_bounds__(256)
void gemm_bt(const void* __restrict__ Ap,
             const void* __restrict__ Btp,
             const float* __restrict__ bias,
             void* __restrict__ Cout,
             int nBase)
{
    __shared__ __align__(16) unsigned short As[128 * 32];
    __shared__ __align__(16) unsigned short Bs[128 * 32];
    gemm_body<MODE>(Ap, Btp, bias, Cout, nBase,
                    blockIdx.x, blockIdx.y, blockIdx.z, As, Bs);
}

// Fused launch: z<2 -> v-proj chunk cV (MODE 3); z>=2 -> out-proj chunk cO
// (MODE 4). The two are independent (V_k vs O_{k-1}); grids share one kernel
// so both run at 768 blocks instead of 2x384.
__global__ __launch_bounds__(256)
void fused_vo(const float* __restrict__ x, const unsigned short* __restrict__ wv,
              const float* __restrict__ bv, unsigned short* __restrict__ vt,
              const unsigned short* __restrict__ ctx,
              const unsigned short* __restrict__ wo,
              const float* __restrict__ bo, float* __restrict__ outp,
              int cV, int cO)
{
    __shared__ __align__(16) unsigned short As[128 * 32];
    __shared__ __align__(16) unsigned short Bs[128 * 32];
    if (blockIdx.z < 2)
        gemm_body<3>(x, wv, bv, vt, cV, blockIdx.x, blockIdx.y, blockIdx.z, As, Bs);
    else
        gemm_body<4>(ctx, wo, bo, outp, cO, blockIdx.x, blockIdx.y,
                     blockIdx.z - 2, As, Bs);
}

// ---------------------------------------------------------------------------
// f32 -> bf16 bulk convert, 8 elems/thread. n multiple of 2048.
// ---------------------------------------------------------------------------
__global__ __launch_bounds__(256)
void cvt_bulk(const float* __restrict__ src, unsigned short* __restrict__ dst, int n)
{
    const int i = (blockIdx.x * 256 + threadIdx.x) * 8;
    if (i >= n) return;
    floatx4 a = ((const floatx4*)(src + i))[0];
    floatx4 b = ((const floatx4*)(src + i))[1];
    *(bf16x8*)(dst + i) = cvt8(a, b);
}

// All 4 weight matrices + bias concat in one launch. 1158 blocks.
__global__ __launch_bounds__(256)
void cvt_weights(const float* __restrict__ Wq, const float* __restrict__ Wk,
                 const float* __restrict__ Wv, const float* __restrict__ Wo,
                 const float* __restrict__ bq, const float* __restrict__ bk,
                 unsigned short* __restrict__ wqk, unsigned short* __restrict__ wvb,
                 unsigned short* __restrict__ wob, float* __restrict__ bqk)
{
    const int gid = blockIdx.x * 256 + threadIdx.x;
    const int W8 = 73728;                     // 589824 / 8
    if (gid < 4 * W8) {
        const int sec = gid / W8, off = (gid - sec * W8) * 8;
        const float* src = (sec == 0) ? Wq : (sec == 1) ? Wk : (sec == 2) ? Wv : Wo;
        unsigned short* dst = (sec == 0) ? wqk : (sec == 1) ? (wqk + 589824)
                              : (sec == 2) ? wvb : wob;
        floatx4 a = ((const floatx4*)(src + off))[0];
        floatx4 b = ((const floatx4*)(src + off))[1];
        *(bf16x8*)(dst + off) = cvt8(a, b);
    } else {
        const int b = gid - 4 * W8;
        if (b < 1536) bqk[b] = (b < 768) ? bq[b] : bk[b - 768];
    }
}

// ---------------------------------------------------------------------------
// T5 relative-position buckets (f32 op order matches reference)
// ---------------------------------------------------------------------------
__global__ __launch_bounds__(256)
void bucket_kernel(const int* __restrict__ dist, int* __restrict__ buckets)
{
    const int idx = blockIdx.x * 256 + threadIdx.x;
    if (idx >= B_ * C_ * C_) return;
    const int dv = dist[idx];
    const int n = dv < 0 ? -dv : dv;
    int bkt;
    if (n < 16) {
        bkt = n;
    } else {
        const float lg = logf((float)n * 0.0625f);        // log(n/16)
        const float t  = (lg / 8.047189562170502f) * 15.0f;
        bkt = 16 + (int)t;
        if (bkt > 31) bkt = 31;
    }
    buckets[idx] = bkt;
}

// ---------------------------------------------------------------------------
// In-place f32 bias + softmax over j. One wave per row.
// ---------------------------------------------------------------------------
__global__ __launch_bounds__(256)
void softmax_bias(float* __restrict__ probs,
                  const int* __restrict__ buckets,
                  const float* __restrict__ rb)
{
    const int wave = threadIdx.x >> 6, lane = threadIdx.x & 63;
    const int rowid = blockIdx.x * 4 + wave;     // [0, 36864)
    const int p = rowid >> 8;
    const int i = rowid & 255;
    const int a = p / 12, b = p - a * 12;        // a = h, b = n
    float* prow = probs + (size_t)rowid * 256;
    const int* brow = buckets + ((size_t)a * 256 + i) * 256;

    float vals[4];
    float mx = -3.4e38f;
#pragma unroll
    for (int t = 0; t < 4; ++t) {
        const int j = t * 64 + lane;
        vals[t] = prow[j] + rb[brow[j] * 12 + b];
        mx = fmaxf(mx, vals[t]);
    }
#pragma unroll
    for (int off = 32; off > 0; off >>= 1) mx = fmaxf(mx, __shfl_xor(mx, off, 64));
    float sum = 0.f;
#pragma unroll
    for (int t = 0; t < 4; ++t) { vals[t] = expf(vals[t] - mx); sum += vals[t]; }
#pragma unroll
    for (int off = 32; off > 0; off >>= 1) sum += __shfl_xor(sum, off, 64);
    const float inv = 1.f / sum;
#pragma unroll
    for (int t = 0; t < 4; ++t) prow[t * 64 + lane] = vals[t] * inv;
}

// ---------------------------------------------------------------------------
// Memory plan.
// d_out (188,743,680 B):
//   out f32   [0 : 150,994,944)  -- final; before out-proj doubles as:
//     q_s bf16 [0 : 75,497,472)            ([n][h][i][rd] layout)
//     k_s bf16 [75,497,472 : 150,994,944)
//   probs f32 [150,994,944 : 188,743,680)  -- BEFORE scores: x_bf half
//     (24576 x 768 bf16 = 37,748,736 B exactly); then scores -> softmax
//     in place (final output).
// d_ws (28,311,552 B):
//   wo_bf   @ 0          (1,179,648)   [live to end]
//   wv_bf   @ 1,179,648  (1,179,648)   [live to last V]
//   bqk f32 @ 2,359,296  (6,144)
//   wqk_bf  @ 2,365,440  (2,359,296)   [dead after qk-proj]
//   buckets @ 4,724,736  (3,145,728)   [dead after softmax]
//   phase3: vt  @ 2,365,440  (12,582,912)  [over wqk_bf+buckets]
//           ctx @ 14,948,352 (12,582,912)  -> ends 27,531,264 <= ws_size
// Phase 3 pipeline: V0, PV0, [V1|O0], PV1, [V2|O1], ..., [V5|O4], PV5, O5.
// vt written in launch k is consumed by PV k before next fused write; ctx
// written by PV k is consumed by O_k inside fused launch k+1 before PV k+1.
// ---------------------------------------------------------------------------
extern "C" void kernel_launch(void* const* d_in, const int* in_sizes, int n_in,
                              void* d_out, int out_size, void* d_ws, size_t ws_size,
                              hipStream_t stream)
{
    const float* x    = (const float*)d_in[0];
    const int*   dist = (const int*)d_in[1];
    const float* Wq   = (const float*)d_in[2];
    const float* bq   = (const float*)d_in[3];
    const float* Wk   = (const float*)d_in[4];
    const float* bk   = (const float*)d_in[5];
    const float* Wv   = (const float*)d_in[6];
    const float* bv   = (const float*)d_in[7];
    const float* Wo   = (const float*)d_in[8];
    const float* bo   = (const float*)d_in[9];
    const float* rb   = (const float*)d_in[10];

    float* outp  = (float*)d_out;
    float* probs = (float*)d_out + (size_t)TOK * E_;      // f32 elem 37,748,736

    unsigned short* qs   = (unsigned short*)d_out;        // [n][h][i][rd]
    unsigned short* x_bf = (unsigned short*)probs;        // x half, pre-scores

    char* ws = (char*)d_ws;
    unsigned short* wo_bf  = (unsigned short*)(ws);
    unsigned short* wv_bf  = (unsigned short*)(ws + 1179648);
    float*          bqk    = (float*)(ws + 2359296);
    unsigned short* wqk_bf = (unsigned short*)(ws + 2365440);
    int*            buckets= (int*)(ws + 4724736);
    unsigned short* vt     = (unsigned short*)(ws + 2365440);   // reuse
    unsigned short* ctx    = (unsigned short*)(ws + 14948352);

    dim3 blk(256);

    cvt_weights<<<dim3(1158), blk, 0, stream>>>(Wq, Wk, Wv, Wo, bq, bk,
                                                wqk_bf, wv_bf, wo_bf, bqk);
    bucket_kernel<<<dim3(3072), blk, 0, stream>>>(dist, buckets);

    // Phase 1: per-half {cvt x -> bf16 in probs region, fused q+k proj (AGL)}
    for (int half = 0; half < 2; ++half) {
        cvt_bulk<<<dim3(9216), blk, 0, stream>>>(
            x + (size_t)half * HALF_TOK * 768, x_bf, HALF_TOK * 768);
        gemm_bt<0><<<dim3(12, 192), blk, 0, stream>>>(x_bf, wqk_bf, bqk, qs, half);
    }
    // scores (overwrites x_bf region with probs)
    gemm_bt<1><<<dim3(2, 2, 144), blk, 0, stream>>>(
        qs, (unsigned short*)d_out + QK_HALF, nullptr, probs, 0);

    // Phase 2: f32 bias + softmax in place (all pairs)
    softmax_bias<<<dim3(9216), blk, 0, stream>>>(probs, buckets, rb);

    // Phase 3 pipeline
    gemm_bt<3><<<dim3(6, 32, 2), blk, 0, stream>>>(x, wv_bf, bv, vt, 0);
    gemm_bt<2><<<dim3(8, 2, 24), blk, 0, stream>>>(probs, vt, nullptr, ctx, 0);
    for (int k = 1; k < 6; ++k) {
        fused_vo<<<dim3(6, 32, 4), blk, 0, stream>>>(
            x, wv_bf, bv, vt, ctx, wo_bf, bo, outp, 2 * k, 2 * (k - 1));
        gemm_bt<2><<<dim3(8, 2, 24), blk, 0, stream>>>(probs, vt, nullptr, ctx, 2 * k);
    }
    gemm_bt<4><<<dim3(6, 32, 2), blk, 0, stream>>>(ctx, wo_bf, bo, outp, 10);
}

// Round 7
// 872.441 us; speedup vs baseline: 2.5528x; 1.0010x over previous
//
#include <hip/hip_runtime.h>
#include <stdint.h>
#include <math.h>

#define R_ 16
#define C_ 256
#define B_ 12
#define E_ 768
#define H_ 12
#define D_ 64
#define TOK (R_*C_*B_)          // 49152
#define HALF_TOK 24576

#define VT_N_ELEMS 3145728     // 12h * 1024rd * 256j shorts per n
#define CTX_N_ELEMS 3145728    // 4096 tok * 768 shorts per n
#define QK_HALF 37748736       // shorts per q or k buffer (49152*768)

typedef __bf16 bf16x8 __attribute__((ext_vector_type(8)));
typedef float floatx4 __attribute__((ext_vector_type(4)));

__device__ __forceinline__ unsigned short f2bf(float f) {
    union { unsigned int i; float f; } v; v.f = f;
    unsigned int i = v.i;
    return (unsigned short)((i + 0x7fffu + ((i >> 16) & 1u)) >> 16);  // RNE
}
__device__ __forceinline__ bf16x8 cvt8(floatx4 lo, floatx4 hi) {
    bf16x8 r;
    r[0] = (__bf16)lo[0]; r[1] = (__bf16)lo[1]; r[2] = (__bf16)lo[2]; r[3] = (__bf16)lo[3];
    r[4] = (__bf16)hi[0]; r[5] = (__bf16)hi[1]; r[6] = (__bf16)hi[2]; r[7] = (__bf16)hi[3];
    return r;
}
__device__ __forceinline__ void gload16(const unsigned short* g, unsigned short* l) {
    __builtin_amdgcn_global_load_lds(
        (const __attribute__((address_space(1))) unsigned int*)g,
        (__attribute__((address_space(3))) unsigned int*)l, 16, 0, 0);
}

// ---------------------------------------------------------------------------
// 128x128 A*B^T GEMM body. B is ALWAYS bf16 via global_load_lds(16B).
// A via global_load_lds for MODE 0/4 (bf16 src), f32-load+cvt+ds_write else.
// LDS k-chunk XOR swizzle on global SOURCE addr (kko), inverse on frag read.
// XCD swizzle: same (lin%8) => same XCD; within XCD, col-fastest panels.
//
// MODE 0: q+k proj, HALF of tokens. A = x_bf bf16 [24576][768] (half nBase);
//         Bt = wqk_bf [1536][768]; grid (12,192).
//         out bf16 q_s/k_s[((n*12+h)*256+i)*1024 + r*64+d] (global token).
// MODE 2: PV (chunk of 2 n). z=nn*12+h. A=probs f32 (cvt), K=256;
//         Bt = vt[((nn*12+h)*1024+rd)*256+j]. grid (8,2,24).
//         out bf16 ctx[nn][(r*256+i)*768 + h*64+d].
// MODE 3: v proj (chunk). z=nn. A = x f32 rows (m*12+n); Bt = wv_bf.
//         grid (6,32,2). out bf16 vt[nn][(h*1024+r*64+d)*256 + j].
// MODE 4: out proj (chunk). z=nn. A = ctx[nn] bf16; Bt = wo_bf.
//         grid (6,32,2). f32 out rows (m*12+n).
// ---------------------------------------------------------------------------
template<int MODE>
__device__ __forceinline__ void gemm_body(const void* __restrict__ Ap,
                                          const void* __restrict__ Btp,
                                          const float* __restrict__ bias,
                                          void* __restrict__ Cout,
                                          int nBase, int rbx, int rby, int rbz,
                                          unsigned short* As, unsigned short* Bs)
{
    constexpr bool AGL = (MODE == 0 || MODE == 4);
    constexpr int K = (MODE == 2) ? 256 : 768;
    constexpr int kIters = K >> 5;
    constexpr int GX = (MODE==0) ? 12 : (MODE==2) ? 8 : 6;
    constexpr int GY = (MODE==0) ? 192 : (MODE==2) ? 2 : 32;
    constexpr int GZ = (MODE==0) ? 1 : (MODE==2) ? 24 : 2;

    const int tid  = threadIdx.x;
    const int wave = tid >> 6, lane = tid & 63;
    const int quad = lane >> 4, l15 = lane & 15;
    const int wr = wave >> 1, wc = wave & 1;

    const int lin = (rbz * GY + rby) * GX + rbx;
    const int tt  = (lin & 7) * ((GX * GY * GZ) >> 3) + (lin >> 3);
    const int bx  = tt % GX;
    const int rem = tt / GX;
    const int by  = rem % GY, bz = rem / GY;
    const int row0 = by * 128, col0 = bx * 128;

    int hIdx = 0, nn = 0, nIdx = 0;
    if (MODE == 2) { hIdx = bz % 12; nn = bz / 12; nIdx = nBase + nn; }
    if (MODE == 3 || MODE == 4) { nn = bz; nIdx = nBase + nn; }

    // staging: slot idx = it*256+tid -> row = idx>>2, ck = idx&3.
    // LDS slot (row,ck) holds logical k-chunk (ck ^ sw), sw = (row>>1)&3.
    const int rA0 = tid >> 2;
    const int ck  = tid & 3;
    const int sw  = (tid >> 3) & 3;
    const int kko = ((ck ^ sw) << 3);      // element offset of sourced chunk

    // ---- B row base pointers (bf16, GL) ----
    const unsigned short* Bt = (const unsigned short*)Btp;
    const unsigned short *gB0, *gB1;
    if (MODE == 2) {
        gB0 = Bt + (((size_t)nn * 12 + hIdx) * 1024 + col0 + rA0) * 256 + kko;
        gB1 = Bt + (((size_t)nn * 12 + hIdx) * 1024 + col0 + rA0 + 64) * 256 + kko;
    } else {
        gB0 = Bt + (size_t)(col0 + rA0) * 768 + kko;
        gB1 = Bt + (size_t)(col0 + rA0 + 64) * 768 + kko;
    }

    // ---- A row base pointers ----
    const unsigned short* gA0u = nullptr; const unsigned short* gA1u = nullptr;
    const float* gA0f = nullptr; const float* gA1f = nullptr;
    if (MODE == 0) {
        gA0u = (const unsigned short*)Ap + (size_t)(row0 + rA0) * 768 + kko;
        gA1u = (const unsigned short*)Ap + (size_t)(row0 + rA0 + 64) * 768 + kko;
    } else if (MODE == 4) {
        gA0u = (const unsigned short*)Ap + (size_t)nn * CTX_N_ELEMS
               + (size_t)(row0 + rA0) * 768 + kko;
        gA1u = (const unsigned short*)Ap + (size_t)nn * CTX_N_ELEMS
               + (size_t)(row0 + rA0 + 64) * 768 + kko;
    } else if (MODE == 3) {
        gA0f = (const float*)Ap + ((size_t)(row0 + rA0) * 12 + nIdx) * 768 + kko;
        gA1f = (const float*)Ap + ((size_t)(row0 + rA0 + 64) * 12 + nIdx) * 768 + kko;
    } else { // MODE 2
        gA0f = (const float*)Ap + ((size_t)(hIdx * 12 + nIdx)) * 65536
               + (size_t)(row0 + rA0) * 256 + kko;
        gA1f = (const float*)Ap + ((size_t)(hIdx * 12 + nIdx)) * 65536
               + (size_t)(row0 + rA0 + 64) * 256 + kko;
    }

    // wave-uniform LDS bases for gload_lds (lane deposits at base + lane*16B)
    unsigned short* lA0 = As + wave * 512;
    unsigned short* lA1 = As + 2048 + wave * 512;
    unsigned short* lB0 = Bs + wave * 512;
    unsigned short* lB1 = Bs + 2048 + wave * 512;

    const floatx4 zero = {0.f, 0.f, 0.f, 0.f};
    floatx4 acc[4][4];
#pragma unroll
    for (int i = 0; i < 4; ++i)
#pragma unroll
        for (int j = 0; j < 4; ++j) acc[i][j] = zero;

    // fragment read swizzle: chunk = quad ^ ((l15>>1)&3)
    const int chO = ((quad ^ ((l15 >> 1) & 3)) << 3);   // shorts

    floatx4 u0l = zero, u0h = zero, u1l = zero, u1h = zero;
    floatx4 p0l = zero, p0h = zero, p1l = zero, p1h = zero;
    if (!AGL) {
        u0l = *(const floatx4*)(gA0f);     u0h = *(const floatx4*)(gA0f + 4);
        u1l = *(const floatx4*)(gA1f);     u1h = *(const floatx4*)(gA1f + 4);
    }

#define GSTEP(KT, UL0, UH0, UL1, UH1, PL0, PH0, PL1, PH1)                         \
    {                                                                              \
        __syncthreads();  /* prev LDS readers done */                              \
        gload16(gB0 + (KT) * 32, lB0);                                             \
        gload16(gB1 + (KT) * 32, lB1);                                             \
        if (AGL) {                                                                 \
            gload16(gA0u + (KT) * 32, lA0);                                        \
            gload16(gA1u + (KT) * 32, lA1);                                        \
        } else {                                                                   \
            *(bf16x8*)(As + tid * 8)        = cvt8(UL0, UH0);                      \
            *(bf16x8*)(As + 2048 + tid * 8) = cvt8(UL1, UH1);                      \
        }                                                                          \
        __syncthreads();  /* LDS tiles valid */                                    \
        if (!AGL && ((KT) + 1 < kIters)) {  /* prefetch overlaps MFMA */           \
            PL0 = *(const floatx4*)(gA0f + ((KT) + 1) * 32);                       \
            PH0 = *(const floatx4*)(gA0f + ((KT) + 1) * 32 + 4);                   \
            PL1 = *(const floatx4*)(gA1f + ((KT) + 1) * 32);                       \
            PH1 = *(const floatx4*)(gA1f + ((KT) + 1) * 32 + 4);                   \
        }                                                                          \
        bf16x8 af[4], bfr[4];                                                      \
        _Pragma("unroll")                                                          \
        for (int t = 0; t < 4; ++t) {                                              \
            af[t]  = *(const bf16x8*)(As + (wr * 64 + t * 16 + l15) * 32 + chO);   \
            bfr[t] = *(const bf16x8*)(Bs + (wc * 64 + t * 16 + l15) * 32 + chO);   \
        }                                                                          \
        _Pragma("unroll")                                                          \
        for (int tm = 0; tm < 4; ++tm)                                             \
            _Pragma("unroll")                                                      \
            for (int tn = 0; tn < 4; ++tn)                                         \
                acc[tm][tn] = __builtin_amdgcn_mfma_f32_16x16x32_bf16(             \
                    af[tm], bfr[tn], acc[tm][tn], 0, 0, 0);                        \
    }

    for (int kt = 0; kt < kIters; kt += 2) {
        GSTEP(kt,     u0l, u0h, u1l, u1h, p0l, p0h, p1l, p1h);
        GSTEP(kt + 1, p0l, p0h, p1l, p1h, u0l, u0h, u1l, u1h);
    }
#undef GSTEP

    // Epilogue. C/D layout: col = lane&15, row = quad*4 + reg.
#pragma unroll
    for (int tm = 0; tm < 4; ++tm) {
        const int rbase = row0 + wr * 64 + tm * 16 + quad * 4;
#pragma unroll
        for (int tn = 0; tn < 4; ++tn) {
            const int cc = col0 + wc * 64 + tn * 16 + l15;
#pragma unroll
            for (int rr = 0; rr < 4; ++rr) {
                float vv = acc[tm][tn][rr];
                const int rowg = rbase + rr;
                if (MODE == 0) {     // q_s/k_s[((n*12+h)*256+i)*1024 + r*64+d]
                    const int tg = nBase * HALF_TOK + rowg;   // global token
                    const int m = tg / 12, n = tg - m * 12;
                    const int r = m >> 8, i = m & 255;
                    const int sel = cc >= 768 ? 1 : 0;
                    const int ccl = cc - sel * 768;
                    const int h = ccl >> 6, d = ccl & 63;
                    ((unsigned short*)Cout)[(size_t)sel * QK_HALF
                        + ((size_t)(n * 12 + h) * 256 + i) * 1024 + r * 64 + d]
                        = f2bf(vv + bias[cc]);
                } else if (MODE == 2) {   // ctx[nn][(r*256+i)*768 + h*64+d]
                    ((unsigned short*)Cout)[(size_t)nn * CTX_N_ELEMS
                        + (((size_t)(cc >> 6)) * 256 + rowg) * 768
                        + hIdx * 64 + (cc & 63)] = f2bf(vv);
                } else if (MODE == 3) {   // vt[nn][(h*1024 + r*64+d)*256 + j]
                    ((unsigned short*)Cout)[(size_t)nn * VT_N_ELEMS
                        + (((size_t)(cc >> 6)) * 1024
                           + (rowg >> 8) * 64 + (cc & 63)) * 256
                        + (rowg & 255)] = f2bf(vv + bias[cc]);
                } else {                  // MODE 4: f32 out rows (m*12+n)
                    ((float*)Cout)[((size_t)rowg * 12 + nIdx) * 768 + cc] = vv + bias[cc];
                }
            }
        }
    }
}

template<int MODE>
__global__ __launch_bounds__(256)
void gemm_bt(const void* __restrict__ Ap,
             const void* __restrict__ Btp,
             const float* __restrict__ bias,
             void* __restrict__ Cout,
             int nBase)
{
    __shared__ __align__(16) unsigned short As[128 * 32];
    __shared__ __align__(16) unsigned short Bs[128 * 32];
    gemm_body<MODE>(Ap, Btp, bias, Cout, nBase,
                    blockIdx.x, blockIdx.y, blockIdx.z, As, Bs);
}

// Fused launch: z<2 -> v-proj chunk cV (MODE 3); z>=2 -> out-proj chunk cO
// (MODE 4). Independent (V_k vs O_{k-1}); 768 blocks instead of 2x384.
__global__ __launch_bounds__(256)
void fused_vo(const float* __restrict__ x, const unsigned short* __restrict__ wv,
              const float* __restrict__ bv, unsigned short* __restrict__ vt,
              const unsigned short* __restrict__ ctx,
              const unsigned short* __restrict__ wo,
              const float* __restrict__ bo, float* __restrict__ outp,
              int cV, int cO)
{
    __shared__ __align__(16) unsigned short As[128 * 32];
    __shared__ __align__(16) unsigned short Bs[128 * 32];
    if (blockIdx.z < 2)
        gemm_body<3>(x, wv, bv, vt, cV, blockIdx.x, blockIdx.y, blockIdx.z, As, Bs);
    else
        gemm_body<4>(ctx, wo, bo, outp, cO, blockIdx.x, blockIdx.y,
                     blockIdx.z - 2, As, Bs);
}

// ---------------------------------------------------------------------------
// Fused scores + bias + softmax. Tile 128 rows x 256 cols (FULL softmax rows
// in-block). 512 threads = 8 waves; wave w owns rows [w*16, w*16+16), all 256
// cols: acc[16] (one 16x16 tile per col-tile). Both operands AGL, K=1024.
// grid (1,2,144): z = n*12+h (matches q_s/k_s pair-block layout); 288 blocks
// (8 | 288 -> bijective XCD swizzle; a pair's 2 row-blocks share an XCD for
// k-panel L2 reuse).
// Epilogue: s = acc*0.03125 + rb[bkt[h][i][j]][n]; row max/exp/sum via
// 16-lane shfl_xor tree (bits 0..3); write probs f32 (final output values).
// ---------------------------------------------------------------------------
__global__ __launch_bounds__(512)
void scores_sm(const unsigned short* __restrict__ q,
               const unsigned short* __restrict__ k,
               const int* __restrict__ buckets,
               const float* __restrict__ rb,
               float* __restrict__ probs)
{
    __shared__ __align__(16) unsigned short As[128 * 32];   //  8 KB
    __shared__ __align__(16) unsigned short Bs[256 * 32];   // 16 KB

    const int tid  = threadIdx.x;
    const int w    = tid >> 6, lane = tid & 63;
    const int quad = lane >> 4, l15 = lane & 15;

    // XCD swizzle (GX=1, GY=2, GZ=144)
    const int lin = (int)blockIdx.z * 2 + (int)blockIdx.y;
    const int tt  = (lin & 7) * 36 + (lin >> 3);
    const int by  = tt % 2, bz = tt / 2;
    const int row0 = by * 128;
    const int h = bz % 12, n = bz / 12;

    // staging geometry (same XOR swizzle as gemm_body)
    const int rA0 = tid >> 2;              // A row 0..127  /  B row (it=0)
    const int ck  = tid & 3;
    const int sw  = (tid >> 3) & 3;
    const int kko = ((ck ^ sw) << 3);

    const unsigned short* gA  = q + ((size_t)bz * 256 + row0 + rA0) * 1024 + kko;
    const unsigned short* gB0 = k + ((size_t)bz * 256 + rA0) * 1024 + kko;
    const unsigned short* gB1 = k + ((size_t)bz * 256 + rA0 + 128) * 1024 + kko;

    unsigned short* lA  = As + w * 512;
    unsigned short* lB0 = Bs + w * 512;
    unsigned short* lB1 = Bs + 4096 + w * 512;

    const floatx4 zero = {0.f, 0.f, 0.f, 0.f};
    floatx4 acc[16];
#pragma unroll
    for (int t = 0; t < 16; ++t) acc[t] = zero;

    const int chO = ((quad ^ ((l15 >> 1) & 3)) << 3);

    for (int kt = 0; kt < 32; ++kt) {
        __syncthreads();
        gload16(gA  + kt * 32, lA);
        gload16(gB0 + kt * 32, lB0);
        gload16(gB1 + kt * 32, lB1);
        __syncthreads();
        const bf16x8 af = *(const bf16x8*)(As + (w * 16 + l15) * 32 + chO);
#pragma unroll
        for (int tn = 0; tn < 16; ++tn) {
            const bf16x8 bfr = *(const bf16x8*)(Bs + (tn * 16 + l15) * 32 + chO);
            acc[tn] = __builtin_amdgcn_mfma_f32_16x16x32_bf16(af, bfr, acc[tn], 0, 0, 0);
        }
    }

    // ---- fused bias + softmax epilogue ----
    // lane holds rows i0+rr (rr=0..3), cols tn*16+l15.
    const int i0 = row0 + w * 16 + quad * 4;
    float mx[4] = {-3.4e38f, -3.4e38f, -3.4e38f, -3.4e38f};
#pragma unroll
    for (int tn = 0; tn < 16; ++tn) {
        const int j = tn * 16 + l15;
#pragma unroll
        for (int rr = 0; rr < 4; ++rr) {
            const int bkt = buckets[((size_t)h * 256 + i0 + rr) * 256 + j];
            const float s = acc[tn][rr] * 0.03125f + rb[bkt * 12 + n];
            acc[tn][rr] = s;
            mx[rr] = fmaxf(mx[rr], s);
        }
    }
#pragma unroll
    for (int rr = 0; rr < 4; ++rr)
#pragma unroll
        for (int off = 1; off < 16; off <<= 1)
            mx[rr] = fmaxf(mx[rr], __shfl_xor(mx[rr], off, 64));
    float sm[4] = {0.f, 0.f, 0.f, 0.f};
#pragma unroll
    for (int tn = 0; tn < 16; ++tn)
#pragma unroll
        for (int rr = 0; rr < 4; ++rr) {
            const float e = expf(acc[tn][rr] - mx[rr]);
            acc[tn][rr] = e;
            sm[rr] += e;
        }
#pragma unroll
    for (int rr = 0; rr < 4; ++rr)
#pragma unroll
        for (int off = 1; off < 16; off <<= 1)
            sm[rr] += __shfl_xor(sm[rr], off, 64);
    float inv[4];
#pragma unroll
    for (int rr = 0; rr < 4; ++rr) inv[rr] = 1.f / sm[rr];

    float* prow = probs + ((size_t)(h * 12 + n)) * 65536;
#pragma unroll
    for (int tn = 0; tn < 16; ++tn) {
        const int j = tn * 16 + l15;
#pragma unroll
        for (int rr = 0; rr < 4; ++rr)
            prow[(size_t)(i0 + rr) * 256 + j] = acc[tn][rr] * inv[rr];
    }
}

// ---------------------------------------------------------------------------
// f32 -> bf16 bulk convert, 8 elems/thread. n multiple of 2048.
// ---------------------------------------------------------------------------
__global__ __launch_bounds__(256)
void cvt_bulk(const float* __restrict__ src, unsigned short* __restrict__ dst, int n)
{
    const int i = (blockIdx.x * 256 + threadIdx.x) * 8;
    if (i >= n) return;
    floatx4 a = ((const floatx4*)(src + i))[0];
    floatx4 b = ((const floatx4*)(src + i))[1];
    *(bf16x8*)(dst + i) = cvt8(a, b);
}

// All 4 weight matrices + bias concat in one launch. 1158 blocks.
__global__ __launch_bounds__(256)
void cvt_weights(const float* __restrict__ Wq, const float* __restrict__ Wk,
                 const float* __restrict__ Wv, const float* __restrict__ Wo,
                 const float* __restrict__ bq, const float* __restrict__ bk,
                 unsigned short* __restrict__ wqk, unsigned short* __restrict__ wvb,
                 unsigned short* __restrict__ wob, float* __restrict__ bqk)
{
    const int gid = blockIdx.x * 256 + threadIdx.x;
    const int W8 = 73728;                     // 589824 / 8
    if (gid < 4 * W8) {
        const int sec = gid / W8, off = (gid - sec * W8) * 8;
        const float* src = (sec == 0) ? Wq : (sec == 1) ? Wk : (sec == 2) ? Wv : Wo;
        unsigned short* dst = (sec == 0) ? wqk : (sec == 1) ? (wqk + 589824)
                              : (sec == 2) ? wvb : wob;
        floatx4 a = ((const floatx4*)(src + off))[0];
        floatx4 b = ((const floatx4*)(src + off))[1];
        *(bf16x8*)(dst + off) = cvt8(a, b);
    } else {
        const int b = gid - 4 * W8;
        if (b < 1536) bqk[b] = (b < 768) ? bq[b] : bk[b - 768];
    }
}

// ---------------------------------------------------------------------------
// T5 relative-position buckets (f32 op order matches reference)
// ---------------------------------------------------------------------------
__global__ __launch_bounds__(256)
void bucket_kernel(const int* __restrict__ dist, int* __restrict__ buckets)
{
    const int idx = blockIdx.x * 256 + threadIdx.x;
    if (idx >= B_ * C_ * C_) return;
    const int dv = dist[idx];
    const int n = dv < 0 ? -dv : dv;
    int bkt;
    if (n < 16) {
        bkt = n;
    } else {
        const float lg = logf((float)n * 0.0625f);        // log(n/16)
        const float t  = (lg / 8.047189562170502f) * 15.0f;
        bkt = 16 + (int)t;
        if (bkt > 31) bkt = 31;
    }
    buckets[idx] = bkt;
}

// ---------------------------------------------------------------------------
// Memory plan.
// d_out (188,743,680 B):
//   out f32   [0 : 150,994,944)  -- final; before out-proj doubles as:
//     q_s bf16 [0 : 75,497,472)            ([n][h][i][rd] layout)
//     k_s bf16 [75,497,472 : 150,994,944)
//   probs f32 [150,994,944 : 188,743,680)  -- BEFORE scores: x_bf half
//     (24576 x 768 bf16 = 37,748,736 B exactly); then scores_sm writes the
//     final softmaxed probs directly (no separate softmax pass).
// d_ws (28,311,552 B):
//   wo_bf   @ 0          (1,179,648)   [live to end]
//   wv_bf   @ 1,179,648  (1,179,648)   [live to last V]
//   bqk f32 @ 2,359,296  (6,144)
//   wqk_bf  @ 2,365,440  (2,359,296)   [dead after qk-proj]
//   buckets @ 4,724,736  (3,145,728)   [dead after scores_sm]
//   phase3: vt  @ 2,365,440  (12,582,912)  [over wqk_bf+buckets]
//           ctx @ 14,948,352 (12,582,912)  -> ends 27,531,264 <= ws_size
// Phase 3 pipeline: V0, PV0, [V1|O0], PV1, ..., [V5|O4], PV5, O5.
// ---------------------------------------------------------------------------
extern "C" void kernel_launch(void* const* d_in, const int* in_sizes, int n_in,
                              void* d_out, int out_size, void* d_ws, size_t ws_size,
                              hipStream_t stream)
{
    const float* x    = (const float*)d_in[0];
    const int*   dist = (const int*)d_in[1];
    const float* Wq   = (const float*)d_in[2];
    const float* bq   = (const float*)d_in[3];
    const float* Wk   = (const float*)d_in[4];
    const float* bk   = (const float*)d_in[5];
    const float* Wv   = (const float*)d_in[6];
    const float* bv   = (const float*)d_in[7];
    const float* Wo   = (const float*)d_in[8];
    const float* bo   = (const float*)d_in[9];
    const float* rb   = (const float*)d_in[10];

    float* outp  = (float*)d_out;
    float* probs = (float*)d_out + (size_t)TOK * E_;      // f32 elem 37,748,736

    unsigned short* qs   = (unsigned short*)d_out;        // [n][h][i][rd]
    unsigned short* ks   = (unsigned short*)d_out + QK_HALF;
    unsigned short* x_bf = (unsigned short*)probs;        // x half, pre-scores

    char* ws = (char*)d_ws;
    unsigned short* wo_bf  = (unsigned short*)(ws);
    unsigned short* wv_bf  = (unsigned short*)(ws + 1179648);
    float*          bqk    = (float*)(ws + 2359296);
    unsigned short* wqk_bf = (unsigned short*)(ws + 2365440);
    int*            buckets= (int*)(ws + 4724736);
    unsigned short* vt     = (unsigned short*)(ws + 2365440);   // reuse
    unsigned short* ctx    = (unsigned short*)(ws + 14948352);

    dim3 blk(256);

    cvt_weights<<<dim3(1158), blk, 0, stream>>>(Wq, Wk, Wv, Wo, bq, bk,
                                                wqk_bf, wv_bf, wo_bf, bqk);
    bucket_kernel<<<dim3(3072), blk, 0, stream>>>(dist, buckets);

    // Phase 1: per-half {cvt x -> bf16 in probs region, fused q+k proj (AGL)}
    for (int half = 0; half < 2; ++half) {
        cvt_bulk<<<dim3(9216), blk, 0, stream>>>(
            x + (size_t)half * HALF_TOK * 768, x_bf, HALF_TOK * 768);
        gemm_bt<0><<<dim3(12, 192), blk, 0, stream>>>(x_bf, wqk_bf, bqk, qs, half);
    }

    // Phase 2: fused scores + bias + softmax (writes final probs f32)
    scores_sm<<<dim3(1, 2, 144), dim3(512), 0, stream>>>(qs, ks, buckets, rb, probs);

    // Phase 3 pipeline
    gemm_bt<3><<<dim3(6, 32, 2), blk, 0, stream>>>(x, wv_bf, bv, vt, 0);
    gemm_bt<2><<<dim3(8, 2, 24), blk, 0, stream>>>(probs, vt, nullptr, ctx, 0);
    for (int k = 1; k < 6; ++k) {
        fused_vo<<<dim3(6, 32, 4), blk, 0, stream>>>(
            x, wv_bf, bv, vt, ctx, wo_bf, bo, outp, 2 * k, 2 * (k - 1));
        gemm_bt<2><<<dim3(8, 2, 24), blk, 0, stream>>>(probs, vt, nullptr, ctx, 2 * k);
    }
    gemm_bt<4><<<dim3(6, 32, 2), blk, 0, stream>>>(ctx, wo_bf, bo, outp, 10);
}